// Round 9
// baseline (507.635 us; speedup 1.0000x reference)
//
#include <hip/hip_runtime.h>

#define NN 50000     // nodes
#define NE 800000    // edges
#define DD 64        // channels
#define NG 512       // graphs
#define NL 5         // layers
#define SCANB 196    // ceil(NN/256)

typedef unsigned short ushort_t;
typedef unsigned int uint_t;

// RNE float -> bf16 (values are finite; no NaN path needed)
__device__ __forceinline__ ushort_t f2bf(float f) {
    uint_t b = __float_as_uint(f);
    return (ushort_t)((b + 0x7fffu + ((b >> 16) & 1u)) >> 16);
}
__device__ __forceinline__ float bflo(uint_t u) { return __uint_as_float(u << 16); }
__device__ __forceinline__ float bfhi(uint_t u) { return __uint_as_float(u & 0xffff0000u); }

// ---------------- x -> bf16 shadow ----------------
__global__ void tobf16_k(const float* __restrict__ x, ushort_t* __restrict__ xb) {
    int i = blockIdx.x * blockDim.x + threadIdx.x;   // float4 index
    if (i < NN * DD / 4) {
        float4 v = ((const float4*)x)[i];
        ushort4 q = { f2bf(v.x), f2bf(v.y), f2bf(v.z), f2bf(v.w) };
        ((ushort4*)xb)[i] = q;
    }
}

// ---------------- CSR build (by dst) ----------------

__global__ void count_deg_k(const int* __restrict__ dst, int* __restrict__ deg) {
    int e = blockIdx.x * blockDim.x + threadIdx.x;
    if (e < NE) atomicAdd(&deg[dst[e]], 1);
}

// ordered exclusive scan of deg -> start (3 kernels, hierarchical)
__global__ void scan1_k(const int* __restrict__ deg, int* __restrict__ start,
                        int* __restrict__ bsum) {
    int i = blockIdx.x * 256 + threadIdx.x;
    int lane = threadIdx.x & 63;
    int wv = threadIdx.x >> 6;
    int d = (i < NN) ? deg[i] : 0;
    int incl = d;
#pragma unroll
    for (int off = 1; off < 64; off <<= 1) {
        int t = __shfl_up(incl, off, 64);
        if (lane >= off) incl += t;
    }
    __shared__ int wsum[4];
    if (lane == 63) wsum[wv] = incl;
    __syncthreads();
    int pre = 0;
#pragma unroll
    for (int w = 0; w < 4; ++w) if (w < wv) pre += wsum[w];
    if (i < NN) start[i] = pre + incl - d;
    if (threadIdx.x == 255) bsum[blockIdx.x] = pre + incl;
}

__global__ void scan2_k(int* __restrict__ bsum, int* __restrict__ boff) {
    int t = threadIdx.x;
    int lane = t & 63;
    int wv = t >> 6;
    int v = (t < SCANB) ? bsum[t] : 0;
    int incl = v;
#pragma unroll
    for (int off = 1; off < 64; off <<= 1) {
        int x = __shfl_up(incl, off, 64);
        if (lane >= off) incl += x;
    }
    __shared__ int wsum[4];
    if (lane == 63) wsum[wv] = incl;
    __syncthreads();
    int pre = 0;
#pragma unroll
    for (int w = 0; w < 4; ++w) if (w < wv) pre += wsum[w];
    if (t < SCANB) boff[t] = pre + incl - v;
}

__global__ void scan3_k(int* __restrict__ start, const int* __restrict__ boff) {
    int i = blockIdx.x * 256 + threadIdx.x;
    if (i < NN) start[i] += boff[blockIdx.x];
}

// plain fill (R7-proven; sliced variant regressed in R8)
__global__ void fill_col_k(const int* __restrict__ src, const int* __restrict__ dst,
                           const int* __restrict__ start, int* __restrict__ fcnt,
                           int* __restrict__ col) {
    int e = blockIdx.x * blockDim.x + threadIdx.x;
    if (e < NE) {
        int d = dst[e];
        int p = atomicAdd(&fcnt[d], 1);
        col[start[d] + p] = src[e];
    }
}

// ---------------- aggregation v4: bf16 gather ----------------
// one wave per node; lanes = 8 edge-groups x 8 channel-octs.
// Per 16-edge chunk: ONE col load (lanes 0..15), nb via __shfl; each lane
// gathers 16 B = 8 bf16 channels of its edge's row; fp32 accumulate.
// Halves the cross-XCD gather traffic vs fp32 rows (R7: 77 MB FETCH).
__global__ void aggregate_k(const ushort_t* __restrict__ hb, const int* __restrict__ start,
                            const int* __restrict__ deg, const int* __restrict__ col,
                            float* __restrict__ agg) {
    int w = (blockIdx.x * blockDim.x + threadIdx.x) >> 6;
    int lane = threadIdx.x & 63;
    if (w >= NN) return;
    int eg = lane >> 3;   // edge group 0..7
    int cl = lane & 7;    // channel oct: floats 8*cl .. 8*cl+7
    int s = start[w], d = deg[w];
    float a0 = 0.f, a1 = 0.f, a2 = 0.f, a3 = 0.f;
    float a4 = 0.f, a5 = 0.f, a6 = 0.f, a7 = 0.f;
    float b0 = 0.f, b1 = 0.f, b2 = 0.f, b3 = 0.f;
    float b4 = 0.f, b5 = 0.f, b6 = 0.f, b7 = 0.f;
    for (int base = 0; base < d; base += 16) {
        int idx = base + (lane & 15);
        int cv = col[s + ((idx < d) ? idx : 0)];   // one load, 16 distinct addrs
        int cnt = d - base;
#pragma unroll
        for (int jj = 0; jj < 2; ++jj) {
            int j = eg + 8 * jj;                   // 0..15 within chunk
            int nb = __shfl(cv, j, 64);
            uint4 v = ((const uint4*)(hb + (size_t)nb * DD))[cl];
            if (j < cnt) {
                if (jj) {
                    b0 += bflo(v.x); b1 += bfhi(v.x); b2 += bflo(v.y); b3 += bfhi(v.y);
                    b4 += bflo(v.z); b5 += bfhi(v.z); b6 += bflo(v.w); b7 += bfhi(v.w);
                } else {
                    a0 += bflo(v.x); a1 += bfhi(v.x); a2 += bflo(v.y); a3 += bfhi(v.y);
                    a4 += bflo(v.z); a5 += bfhi(v.z); a6 += bflo(v.w); a7 += bfhi(v.w);
                }
            }
        }
    }
    a0 += b0; a1 += b1; a2 += b2; a3 += b3;
    a4 += b4; a5 += b5; a6 += b6; a7 += b7;
#pragma unroll
    for (int off = 8; off <= 32; off <<= 1) {
        a0 += __shfl_xor(a0, off, 64); a1 += __shfl_xor(a1, off, 64);
        a2 += __shfl_xor(a2, off, 64); a3 += __shfl_xor(a3, off, 64);
        a4 += __shfl_xor(a4, off, 64); a5 += __shfl_xor(a5, off, 64);
        a6 += __shfl_xor(a6, off, 64); a7 += __shfl_xor(a7, off, 64);
    }
    if (eg == 0) {
        float4* o = (float4*)(agg + (size_t)w * DD);
        o[2 * cl]     = make_float4(a0, a1, a2, a3);
        o[2 * cl + 1] = make_float4(a4, a5, a6, a7);
    }
}

// ---------------- dense layer v4 + bf16 shadow-write ----------------
// out = relu([hin] + agg @ Wrel^T + b + hin @ Wroot^T); also emits bf16 copy
// of out for the next layer's gather.
template <int RESID>
__global__ void __launch_bounds__(256, 3)
dense_layer_k(const float* __restrict__ agg, const float* __restrict__ hin,
              const float* __restrict__ wrel, const float* __restrict__ brel,
              const float* __restrict__ wroot, float* __restrict__ hout,
              ushort_t* __restrict__ hbout) {
    __shared__ float A[64][68];
    __shared__ float H[64][68];

    const int t = threadIdx.x;
    const int tile = blockIdx.x * 64;
    const int nrows = min(64, NN - tile);

    const float4* agg4 = (const float4*)(agg + (size_t)tile * DD);
    const float4* hin4 = (const float4*)(hin + (size_t)tile * DD);
#pragma unroll
    for (int k = 0; k < 4; ++k) {
        int idx = t + k * 256;
        int row = idx >> 4, cq = idx & 15;
        if (row < nrows) {
            *(float4*)&A[row][4 * cq] = agg4[idx];
            *(float4*)&H[row][4 * cq] = hin4[idx];
        }
    }
    __syncthreads();

    const int lane = t & 63;
    const int wv = __builtin_amdgcn_readfirstlane(t >> 6);
    const int o0 = wv * 16;

    float4 a4[8], h4[8];
    float acc[16];

#pragma unroll
    for (int cq = 0; cq < 8; ++cq) {
        a4[cq] = *(const float4*)&A[lane][4 * cq];
        h4[cq] = *(const float4*)&H[lane][4 * cq];
    }
#pragma unroll
    for (int oo = 0; oo < 16; ++oo) {
        int o = o0 + oo;
        const float* w1 = wrel + o * DD;
        const float* w2 = wroot + o * DD;
        float s0 = 0.f, s1 = 0.f, s2 = 0.f, s3 = 0.f;
#pragma unroll
        for (int cq = 0; cq < 8; ++cq) {
            s0 += a4[cq].x * w1[4 * cq + 0] + h4[cq].x * w2[4 * cq + 0];
            s1 += a4[cq].y * w1[4 * cq + 1] + h4[cq].y * w2[4 * cq + 1];
            s2 += a4[cq].z * w1[4 * cq + 2] + h4[cq].z * w2[4 * cq + 2];
            s3 += a4[cq].w * w1[4 * cq + 3] + h4[cq].w * w2[4 * cq + 3];
        }
        acc[oo] = (s0 + s1) + (s2 + s3);
    }

#pragma unroll
    for (int cq = 0; cq < 8; ++cq) {
        a4[cq] = *(const float4*)&A[lane][32 + 4 * cq];
        h4[cq] = *(const float4*)&H[lane][32 + 4 * cq];
    }
    __syncthreads();
    float* Out = &A[0][0];
#pragma unroll
    for (int oo = 0; oo < 16; ++oo) {
        int o = o0 + oo;
        const float* w1 = wrel + o * DD + 32;
        const float* w2 = wroot + o * DD + 32;
        float s0 = acc[oo], s1 = 0.f, s2 = 0.f, s3 = 0.f;
#pragma unroll
        for (int cq = 0; cq < 8; ++cq) {
            s0 += a4[cq].x * w1[4 * cq + 0] + h4[cq].x * w2[4 * cq + 0];
            s1 += a4[cq].y * w1[4 * cq + 1] + h4[cq].y * w2[4 * cq + 1];
            s2 += a4[cq].z * w1[4 * cq + 2] + h4[cq].z * w2[4 * cq + 2];
            s3 += a4[cq].w * w1[4 * cq + 3] + h4[cq].w * w2[4 * cq + 3];
        }
        Out[lane * 68 + o] = (s0 + s1) + (s2 + s3) + brel[o];
    }
    __syncthreads();

    float4* out4 = (float4*)(hout + (size_t)tile * DD);
    ushort4* outb4 = (ushort4*)(hbout + (size_t)tile * DD);
#pragma unroll
    for (int k = 0; k < 4; ++k) {
        int idx = t + k * 256;
        int row = idx >> 4, cq = idx & 15;
        if (row < nrows) {
            float4 r = *(const float4*)&A[row][4 * cq];
            if (RESID) {
                float4 hr = *(const float4*)&H[row][4 * cq];
                r.x += hr.x; r.y += hr.y; r.z += hr.z; r.w += hr.w;
            }
            r.x = fmaxf(r.x, 0.f); r.y = fmaxf(r.y, 0.f);
            r.z = fmaxf(r.z, 0.f); r.w = fmaxf(r.w, 0.f);
            out4[idx] = r;
            ushort4 q = { f2bf(r.x), f2bf(r.y), f2bf(r.z), f2bf(r.w) };
            outb4[idx] = q;
        }
    }
}

// ---------------- pooling (batch is sorted) ----------------

__global__ void pool_k(const float* __restrict__ h, const int* __restrict__ batch,
                       float* __restrict__ sums, int* __restrict__ cnt) {
    const int NP = 32;
    int w = (blockIdx.x * blockDim.x + threadIdx.x) >> 6;
    int lane = threadIdx.x & 63;
    int n0 = w * NP;
    if (n0 >= NN) return;
    int n1 = min(n0 + NP, NN);
    int g = batch[n0];
    float acc = 0.f;
    int run = 0;
    for (int i = n0; i < n1; ++i) {
        int gi = batch[i];
        if (gi != g) {
            atomicAdd(&sums[g * DD + lane], acc);
            if (lane == 0) atomicAdd(&cnt[g], run);
            acc = 0.f; run = 0; g = gi;
        }
        acc += h[i * DD + lane];
        run++;
    }
    atomicAdd(&sums[g * DD + lane], acc);
    if (lane == 0) atomicAdd(&cnt[g], run);
}

// ---------------- head: mean -> linear -> softmax ----------------

__global__ void head_k(const float* __restrict__ sums, const int* __restrict__ cnt,
                       const float* __restrict__ lin_w, const float* __restrict__ lin_b,
                       float* __restrict__ out) {
    int g = blockIdx.x * (blockDim.x >> 6) + (threadIdx.x >> 6);
    int o = threadIdx.x & 63;
    if (g >= NG) return;
    float c = (float)cnt[g];
    float inv = 1.0f / fmaxf(c, 1.0f);
    float acc = lin_b[o];
#pragma unroll 8
    for (int k = 0; k < DD; ++k) {
        acc += sums[g * DD + k] * inv * lin_w[o * DD + k];
    }
    float m = acc;
#pragma unroll
    for (int off = 32; off; off >>= 1) m = fmaxf(m, __shfl_xor(m, off, 64));
    float e = __expf(acc - m);
    float s = e;
#pragma unroll
    for (int off = 32; off; off >>= 1) s += __shfl_xor(s, off, 64);
    out[g * DD + o] = e / s;
}

// ---------------- driver ----------------

extern "C" void kernel_launch(void* const* d_in, const int* in_sizes, int n_in,
                              void* d_out, int out_size, void* d_ws, size_t ws_size,
                              hipStream_t stream) {
    const float* x      = (const float*)d_in[0];
    const int*   edge   = (const int*)d_in[1];   // [2, E]: src = edge, dst = edge+NE
    const int*   batch  = (const int*)d_in[2];
    const float* rel_w  = (const float*)d_in[3]; // [L, D, D]
    const float* rel_b  = (const float*)d_in[4]; // [L, D]
    const float* root_w = (const float*)d_in[5]; // [L, D, D]
    const float* lin_w  = (const float*)d_in[6]; // [D, D]
    const float* lin_b  = (const float*)d_in[7]; // [D]
    float* out = (float*)d_out;

    const int* src = edge;
    const int* dst = edge + NE;

    // workspace carve (all 256B aligned)
    char* p = (char*)d_ws;
    auto carve = [&](size_t bytes) {
        char* r = p;
        p += (bytes + 255) & ~(size_t)255;
        return (void*)r;
    };
    float*    hA   = (float*)carve((size_t)NN * DD * 4);
    float*    hB   = (float*)carve((size_t)NN * DD * 4);
    float*    agg  = (float*)carve((size_t)NN * DD * 4);
    ushort_t* hb   = (ushort_t*)carve((size_t)NN * DD * 2);  // bf16 shadow of current h
    int*      col  = (int*)carve((size_t)NE * 4);
    int*      strt = (int*)carve((size_t)NN * 4);
    int*      bsum = (int*)carve((size_t)SCANB * 4);
    int*      boff = (int*)carve((size_t)SCANB * 4);
    // ---- contiguous zero region (single memset) ----
    char* zbase = p;
    float* sums = (float*)carve((size_t)NG * DD * 4);
    int*   cnt  = (int*)carve((size_t)NG * 4);
    int*   deg  = (int*)carve((size_t)NN * 4);
    int*   fcnt = (int*)carve((size_t)NN * 4);
    size_t zbytes = (size_t)(p - zbase);

    hipMemsetAsync(zbase, 0, zbytes, stream);

    // CSR build: count -> ordered scan -> fill
    count_deg_k<<<(NE + 255) / 256, 256, 0, stream>>>(dst, deg);
    scan1_k<<<SCANB, 256, 0, stream>>>(deg, strt, bsum);
    scan2_k<<<1, 256, 0, stream>>>(bsum, boff);
    scan3_k<<<SCANB, 256, 0, stream>>>(strt, boff);
    fill_col_k<<<(NE + 255) / 256, 256, 0, stream>>>(src, dst, strt, fcnt, col);

    // bf16 shadow of x
    tobf16_k<<<(NN * DD / 4 + 255) / 256, 256, 0, stream>>>(x, hb);

    const int aggBlocks = (NN + 3) / 4;     // 4 waves (nodes) per block
    const int dnsBlocks = (NN + 63) / 64;   // 64 nodes per block

    // layer 0: x -> hA  (hb holds bf16(x), then overwritten with bf16(h1))
    aggregate_k<<<aggBlocks, 256, 0, stream>>>(hb, strt, deg, col, agg);
    dense_layer_k<0><<<dnsBlocks, 256, 0, stream>>>(agg, x, rel_w, rel_b, root_w, hA, hb);
    // layer 1: hA -> hB
    aggregate_k<<<aggBlocks, 256, 0, stream>>>(hb, strt, deg, col, agg);
    dense_layer_k<0><<<dnsBlocks, 256, 0, stream>>>(agg, hA, rel_w + 4096, rel_b + 64,
                                                    root_w + 4096, hB, hb);
    // layer 2: hB -> hA
    aggregate_k<<<aggBlocks, 256, 0, stream>>>(hb, strt, deg, col, agg);
    dense_layer_k<0><<<dnsBlocks, 256, 0, stream>>>(agg, hB, rel_w + 2 * 4096, rel_b + 2 * 64,
                                                    root_w + 2 * 4096, hA, hb);
    // layer 3 (residual): hA -> hB
    aggregate_k<<<aggBlocks, 256, 0, stream>>>(hb, strt, deg, col, agg);
    dense_layer_k<1><<<dnsBlocks, 256, 0, stream>>>(agg, hA, rel_w + 3 * 4096, rel_b + 3 * 64,
                                                    root_w + 3 * 4096, hB, hb);
    // layer 4 (residual): hB -> hA
    aggregate_k<<<aggBlocks, 256, 0, stream>>>(hb, strt, deg, col, agg);
    dense_layer_k<1><<<dnsBlocks, 256, 0, stream>>>(agg, hB, rel_w + 4 * 4096, rel_b + 4 * 64,
                                                    root_w + 4 * 4096, hA, hb);

    // pool + head (fp32 path)
    const int wavesPool = (NN + 31) / 32;
    pool_k<<<(wavesPool + 3) / 4, 256, 0, stream>>>(hA, batch, sums, cnt);
    head_k<<<(NG + 3) / 4, 256, 0, stream>>>(sums, cnt, lin_w, lin_b, out);
}

// Round 10
// 448.525 us; speedup vs baseline: 1.1318x; 1.1318x over previous
//
#include <hip/hip_runtime.h>

#define NN 50000     // nodes
#define NE 800000    // edges
#define DD 64        // channels
#define NG 512       // graphs
#define NL 5         // layers

// ---------------- CSR build (by dst) ----------------

__global__ void count_deg_k(const int* __restrict__ dst, int* __restrict__ deg) {
    int e = blockIdx.x * blockDim.x + threadIdx.x;
    if (e < NE) atomicAdd(&deg[dst[e]], 1);
}

// start[i] = exclusive prefix of deg, allocated via one atomic per wave
// (R7-proven; node ranges contiguous, global order arbitrary — sufficient)
__global__ void calc_start_k(const int* __restrict__ deg, int* __restrict__ start,
                             int* __restrict__ cursor) {
    int i = blockIdx.x * blockDim.x + threadIdx.x;
    int lane = threadIdx.x & 63;
    int d = (i < NN) ? deg[i] : 0;
    int incl = d;
#pragma unroll
    for (int off = 1; off < 64; off <<= 1) {
        int t = __shfl_up(incl, off, 64);
        if (lane >= off) incl += t;
    }
    int total = __shfl(incl, 63, 64);
    int base = 0;
    if (lane == 0 && total > 0) base = atomicAdd(cursor, total);
    base = __shfl(base, 0, 64);
    if (i < NN) start[i] = base + incl - d;
}

__global__ void fill_col_k(const int* __restrict__ src, const int* __restrict__ dst,
                           const int* __restrict__ start, int* __restrict__ fcnt,
                           int* __restrict__ col) {
    int e = blockIdx.x * blockDim.x + threadIdx.x;
    if (e < NE) {
        int d = dst[e];
        int p = atomicAdd(&fcnt[d], 1);
        col[start[d] + p] = src[e];
    }
}

// ---------------- aggregation v5: 32-edge chunks, 8-deep MLP ----------------
// one wave per node; lanes = 4 edge-groups x 16 channel-quads.
// Per 32-edge chunk: ONE col load (lanes 0..31 hold the chunk), nb via
// __shfl; 4 gathers issued unconditionally + 4 more under a wave-uniform
// cnt>16 branch -> up to 8 independent float4 loads in flight before any
// use. (R9 falsified byte-BW-bound; this attacks exposed latency.)
__global__ void aggregate_k(const float* __restrict__ h, const int* __restrict__ start,
                            const int* __restrict__ deg, const int* __restrict__ col,
                            float* __restrict__ agg) {
    int w = (blockIdx.x * blockDim.x + threadIdx.x) >> 6;
    int lane = threadIdx.x & 63;
    if (w >= NN) return;
    int eg = lane >> 4;   // edge group 0..3
    int cl = lane & 15;   // channel quad: floats 4*cl .. 4*cl+3
    int s = start[w], d = deg[w];
    float4 acc0 = make_float4(0.f, 0.f, 0.f, 0.f);
    float4 acc1 = make_float4(0.f, 0.f, 0.f, 0.f);
    const float4* h4 = (const float4*)h;
    for (int base = 0; base < d; base += 32) {
        int idx = base + (lane & 31);
        int cv = col[s + ((idx < d) ? idx : 0)];   // one load, 32 distinct addrs
        int cnt = d - base;                        // >0; wave-uniform
        // first 16 edges of chunk: 4 independent gathers
        float4 v0, v1, v2, v3;
        {
            int n0 = __shfl(cv, eg +  0, 64);
            int n1 = __shfl(cv, eg +  4, 64);
            int n2 = __shfl(cv, eg +  8, 64);
            int n3 = __shfl(cv, eg + 12, 64);
            v0 = h4[(size_t)n0 * 16 + cl];
            v1 = h4[(size_t)n1 * 16 + cl];
            v2 = h4[(size_t)n2 * 16 + cl];
            v3 = h4[(size_t)n3 * 16 + cl];
        }
        float4 v4, v5, v6, v7;
        bool hi = (cnt > 16);                      // wave-uniform branch
        if (hi) {
            int n4 = __shfl(cv, eg + 16, 64);
            int n5 = __shfl(cv, eg + 20, 64);
            int n6 = __shfl(cv, eg + 24, 64);
            int n7 = __shfl(cv, eg + 28, 64);
            v4 = h4[(size_t)n4 * 16 + cl];
            v5 = h4[(size_t)n5 * 16 + cl];
            v6 = h4[(size_t)n6 * 16 + cl];
            v7 = h4[(size_t)n7 * 16 + cl];
        }
        if (eg + 0 < cnt)  { acc0.x += v0.x; acc0.y += v0.y; acc0.z += v0.z; acc0.w += v0.w; }
        if (eg + 4 < cnt)  { acc1.x += v1.x; acc1.y += v1.y; acc1.z += v1.z; acc1.w += v1.w; }
        if (eg + 8 < cnt)  { acc0.x += v2.x; acc0.y += v2.y; acc0.z += v2.z; acc0.w += v2.w; }
        if (eg + 12 < cnt) { acc1.x += v3.x; acc1.y += v3.y; acc1.z += v3.z; acc1.w += v3.w; }
        if (hi) {
            if (eg + 16 < cnt) { acc0.x += v4.x; acc0.y += v4.y; acc0.z += v4.z; acc0.w += v4.w; }
            if (eg + 20 < cnt) { acc1.x += v5.x; acc1.y += v5.y; acc1.z += v5.z; acc1.w += v5.w; }
            if (eg + 24 < cnt) { acc0.x += v6.x; acc0.y += v6.y; acc0.z += v6.z; acc0.w += v6.w; }
            if (eg + 28 < cnt) { acc1.x += v7.x; acc1.y += v7.y; acc1.z += v7.z; acc1.w += v7.w; }
        }
    }
    float4 acc;
    acc.x = acc0.x + acc1.x; acc.y = acc0.y + acc1.y;
    acc.z = acc0.z + acc1.z; acc.w = acc0.w + acc1.w;
#pragma unroll
    for (int off = 16; off <= 32; off <<= 1) {
        acc.x += __shfl_xor(acc.x, off, 64);
        acc.y += __shfl_xor(acc.y, off, 64);
        acc.z += __shfl_xor(acc.z, off, 64);
        acc.w += __shfl_xor(acc.w, off, 64);
    }
    if (eg == 0) {
        ((float4*)(agg + (size_t)w * DD))[cl] = acc;
    }
}

// ---------------- dense layer v4 (proven R5/R7) ----------------
// out = relu([hin] + agg @ Wrel^T + b + hin @ Wroot^T)
// block = 256 = 4 waves, 64 nodes/block. lane = node, wave = 16-output slice.
// Two channel-half passes keep register demand ~105 VGPR (no spill at 3
// blocks/CU). Weights wave-uniform -> scalar s_load; activations in registers.
template <int RESID>
__global__ void __launch_bounds__(256, 3)
dense_layer_k(const float* __restrict__ agg, const float* __restrict__ hin,
              const float* __restrict__ wrel, const float* __restrict__ brel,
              const float* __restrict__ wroot, float* __restrict__ hout) {
    __shared__ float A[64][68];   // stride 68 dwords: b128 transpose reads at 8-phase floor
    __shared__ float H[64][68];

    const int t = threadIdx.x;
    const int tile = blockIdx.x * 64;
    const int nrows = min(64, NN - tile);

    const float4* agg4 = (const float4*)(agg + (size_t)tile * DD);
    const float4* hin4 = (const float4*)(hin + (size_t)tile * DD);
#pragma unroll
    for (int k = 0; k < 4; ++k) {
        int idx = t + k * 256;
        int row = idx >> 4, cq = idx & 15;
        if (row < nrows) {
            *(float4*)&A[row][4 * cq] = agg4[idx];
            *(float4*)&H[row][4 * cq] = hin4[idx];
        }
    }
    __syncthreads();

    const int lane = t & 63;
    const int wv = __builtin_amdgcn_readfirstlane(t >> 6);
    const int o0 = wv * 16;

    float4 a4[8], h4[8];
    float acc[16];

#pragma unroll
    for (int cq = 0; cq < 8; ++cq) {
        a4[cq] = *(const float4*)&A[lane][4 * cq];
        h4[cq] = *(const float4*)&H[lane][4 * cq];
    }
#pragma unroll
    for (int oo = 0; oo < 16; ++oo) {
        int o = o0 + oo;
        const float* w1 = wrel + o * DD;
        const float* w2 = wroot + o * DD;
        float s0 = 0.f, s1 = 0.f, s2 = 0.f, s3 = 0.f;
#pragma unroll
        for (int cq = 0; cq < 8; ++cq) {
            s0 += a4[cq].x * w1[4 * cq + 0] + h4[cq].x * w2[4 * cq + 0];
            s1 += a4[cq].y * w1[4 * cq + 1] + h4[cq].y * w2[4 * cq + 1];
            s2 += a4[cq].z * w1[4 * cq + 2] + h4[cq].z * w2[4 * cq + 2];
            s3 += a4[cq].w * w1[4 * cq + 3] + h4[cq].w * w2[4 * cq + 3];
        }
        acc[oo] = (s0 + s1) + (s2 + s3);
    }

#pragma unroll
    for (int cq = 0; cq < 8; ++cq) {
        a4[cq] = *(const float4*)&A[lane][32 + 4 * cq];
        h4[cq] = *(const float4*)&H[lane][32 + 4 * cq];
    }
    __syncthreads();
    float* Out = &A[0][0];
#pragma unroll
    for (int oo = 0; oo < 16; ++oo) {
        int o = o0 + oo;
        const float* w1 = wrel + o * DD + 32;
        const float* w2 = wroot + o * DD + 32;
        float s0 = acc[oo], s1 = 0.f, s2 = 0.f, s3 = 0.f;
#pragma unroll
        for (int cq = 0; cq < 8; ++cq) {
            s0 += a4[cq].x * w1[4 * cq + 0] + h4[cq].x * w2[4 * cq + 0];
            s1 += a4[cq].y * w1[4 * cq + 1] + h4[cq].y * w2[4 * cq + 1];
            s2 += a4[cq].z * w1[4 * cq + 2] + h4[cq].z * w2[4 * cq + 2];
            s3 += a4[cq].w * w1[4 * cq + 3] + h4[cq].w * w2[4 * cq + 3];
        }
        Out[lane * 68 + o] = (s0 + s1) + (s2 + s3) + brel[o];
    }
    __syncthreads();

    float4* out4 = (float4*)(hout + (size_t)tile * DD);
#pragma unroll
    for (int k = 0; k < 4; ++k) {
        int idx = t + k * 256;
        int row = idx >> 4, cq = idx & 15;
        if (row < nrows) {
            float4 r = *(const float4*)&A[row][4 * cq];
            if (RESID) {
                float4 hr = *(const float4*)&H[row][4 * cq];
                r.x += hr.x; r.y += hr.y; r.z += hr.z; r.w += hr.w;
            }
            r.x = fmaxf(r.x, 0.f); r.y = fmaxf(r.y, 0.f);
            r.z = fmaxf(r.z, 0.f); r.w = fmaxf(r.w, 0.f);
            out4[idx] = r;
        }
    }
}

// ---------------- pooling (batch is sorted) ----------------

__global__ void pool_k(const float* __restrict__ h, const int* __restrict__ batch,
                       float* __restrict__ sums, int* __restrict__ cnt) {
    const int NP = 32;
    int w = (blockIdx.x * blockDim.x + threadIdx.x) >> 6;
    int lane = threadIdx.x & 63;
    int n0 = w * NP;
    if (n0 >= NN) return;
    int n1 = min(n0 + NP, NN);
    int g = batch[n0];
    float acc = 0.f;
    int run = 0;
    for (int i = n0; i < n1; ++i) {
        int gi = batch[i];
        if (gi != g) {
            atomicAdd(&sums[g * DD + lane], acc);
            if (lane == 0) atomicAdd(&cnt[g], run);
            acc = 0.f; run = 0; g = gi;
        }
        acc += h[i * DD + lane];
        run++;
    }
    atomicAdd(&sums[g * DD + lane], acc);
    if (lane == 0) atomicAdd(&cnt[g], run);
}

// ---------------- head: mean -> linear -> softmax ----------------

__global__ void head_k(const float* __restrict__ sums, const int* __restrict__ cnt,
                       const float* __restrict__ lin_w, const float* __restrict__ lin_b,
                       float* __restrict__ out) {
    int g = blockIdx.x * (blockDim.x >> 6) + (threadIdx.x >> 6);
    int o = threadIdx.x & 63;
    if (g >= NG) return;
    float c = (float)cnt[g];
    float inv = 1.0f / fmaxf(c, 1.0f);
    float acc = lin_b[o];
#pragma unroll 8
    for (int k = 0; k < DD; ++k) {
        acc += sums[g * DD + k] * inv * lin_w[o * DD + k];
    }
    float m = acc;
#pragma unroll
    for (int off = 32; off; off >>= 1) m = fmaxf(m, __shfl_xor(m, off, 64));
    float e = __expf(acc - m);
    float s = e;
#pragma unroll
    for (int off = 32; off; off >>= 1) s += __shfl_xor(s, off, 64);
    out[g * DD + o] = e / s;
}

// ---------------- driver ----------------

extern "C" void kernel_launch(void* const* d_in, const int* in_sizes, int n_in,
                              void* d_out, int out_size, void* d_ws, size_t ws_size,
                              hipStream_t stream) {
    const float* x      = (const float*)d_in[0];
    const int*   edge   = (const int*)d_in[1];   // [2, E]: src = edge, dst = edge+NE
    const int*   batch  = (const int*)d_in[2];
    const float* rel_w  = (const float*)d_in[3]; // [L, D, D]
    const float* rel_b  = (const float*)d_in[4]; // [L, D]
    const float* root_w = (const float*)d_in[5]; // [L, D, D]
    const float* lin_w  = (const float*)d_in[6]; // [D, D]
    const float* lin_b  = (const float*)d_in[7]; // [D]
    float* out = (float*)d_out;

    const int* src = edge;
    const int* dst = edge + NE;

    // workspace carve (all 256B aligned)
    char* p = (char*)d_ws;
    auto carve = [&](size_t bytes) {
        char* r = p;
        p += (bytes + 255) & ~(size_t)255;
        return (void*)r;
    };
    float* hA   = (float*)carve((size_t)NN * DD * 4);
    float* hB   = (float*)carve((size_t)NN * DD * 4);
    float* agg  = (float*)carve((size_t)NN * DD * 4);
    int*   col  = (int*)carve((size_t)NE * 4);
    int*   strt = (int*)carve((size_t)NN * 4);
    // ---- contiguous zero region (single memset) ----
    char* zbase = p;
    float* sums = (float*)carve((size_t)NG * DD * 4);
    int*   cnt  = (int*)carve((size_t)NG * 4);
    int*   deg  = (int*)carve((size_t)NN * 4);
    int*   fcnt = (int*)carve((size_t)NN * 4);
    int*   cur  = (int*)carve(4);
    size_t zbytes = (size_t)(p - zbase);

    hipMemsetAsync(zbase, 0, zbytes, stream);

    // CSR build (R7-proven)
    count_deg_k<<<(NE + 255) / 256, 256, 0, stream>>>(dst, deg);
    calc_start_k<<<(NN + 255) / 256, 256, 0, stream>>>(deg, strt, cur);
    fill_col_k<<<(NE + 255) / 256, 256, 0, stream>>>(src, dst, strt, fcnt, col);

    const int aggBlocks = (NN + 3) / 4;     // 4 waves (nodes) per block
    const int dnsBlocks = (NN + 63) / 64;   // 64 nodes per block

    // layer 0: x -> hA
    aggregate_k<<<aggBlocks, 256, 0, stream>>>(x, strt, deg, col, agg);
    dense_layer_k<0><<<dnsBlocks, 256, 0, stream>>>(agg, x, rel_w, rel_b, root_w, hA);
    // layer 1: hA -> hB
    aggregate_k<<<aggBlocks, 256, 0, stream>>>(hA, strt, deg, col, agg);
    dense_layer_k<0><<<dnsBlocks, 256, 0, stream>>>(agg, hA, rel_w + 4096, rel_b + 64,
                                                    root_w + 4096, hB);
    // layer 2: hB -> hA
    aggregate_k<<<aggBlocks, 256, 0, stream>>>(hB, strt, deg, col, agg);
    dense_layer_k<0><<<dnsBlocks, 256, 0, stream>>>(agg, hB, rel_w + 2 * 4096, rel_b + 2 * 64,
                                                    root_w + 2 * 4096, hA);
    // layer 3 (residual): hA -> hB
    aggregate_k<<<aggBlocks, 256, 0, stream>>>(hA, strt, deg, col, agg);
    dense_layer_k<1><<<dnsBlocks, 256, 0, stream>>>(agg, hA, rel_w + 3 * 4096, rel_b + 3 * 64,
                                                    root_w + 3 * 4096, hB);
    // layer 4 (residual): hB -> hA
    aggregate_k<<<aggBlocks, 256, 0, stream>>>(hB, strt, deg, col, agg);
    dense_layer_k<1><<<dnsBlocks, 256, 0, stream>>>(agg, hB, rel_w + 4 * 4096, rel_b + 4 * 64,
                                                    root_w + 4 * 4096, hA);

    // pool + head
    const int wavesPool = (NN + 31) / 32;
    pool_k<<<(wavesPool + 3) / 4, 256, 0, stream>>>(hA, batch, sums, cnt);
    head_k<<<(NG + 3) / 4, 256, 0, stream>>>(sums, cnt, lin_w, lin_b, out);
}